// Round 2
// baseline (100.325 us; speedup 1.0000x reference)
//
#include <hip/hip_runtime.h>
#include <math.h>

// Problem constants: N=4096 rows, S=128 samples (fp32).
#define S 128
#define NROWS 4096
#define WPB 4                      // waves per block (1 row per wave)
#define NBLK (NROWS / WPB)         // 1024 blocks

__device__ __forceinline__ float readlane_f(float v, int lane) {
    return __uint_as_float(__builtin_amdgcn_readlane(__float_as_uint(v), lane));
}

// Single fused kernel: per-row argmin over circular shifts, scale, detail,
// MSE partial; block-combined partials -> 2 global fp32 atomics; last block
// (poison-based counter) writes the final scalar.
__global__ __launch_bounds__(256) void loss3_fused(
    const float* __restrict__ outp,
    const float* __restrict__ trp,
    float* __restrict__ acc,      // d_ws: [0]=A, [1]=B(mse), [2]=counter bits
    float* __restrict__ out) {

    __shared__ float s_tr2[WPB][2 * S];   // truth, doubled for circular reads
    __shared__ float s_out[WPB][S];       // output row (for detail phase)
    __shared__ float s_part[WPB][2];

    const int tid = threadIdx.x;
    const int w = tid >> 6;       // wave id = row within block
    const int l = tid & 63;       // lane
    const int row = blockIdx.x * WPB + w;

    const float* orow = outp + (size_t)row * S;
    const float* trow = trp  + (size_t)row * S;

    const float o_lo = orow[l], o_hi = orow[l + 64];
    const float t_lo = trow[l], t_hi = trow[l + 64];

    s_out[w][l]       = o_lo;  s_out[w][l + 64]  = o_hi;
    s_tr2[w][l]       = t_lo;  s_tr2[w][l + 64]  = t_hi;
    s_tr2[w][l + 128] = t_lo;  s_tr2[w][l + 192] = t_hi;
    __syncthreads();

    const float* tw = s_tr2[w];

    // ---- squared shift-distance for shifts a=l (d0) and a=l+64 (d1).
    // dist[a] = sum_c (out[c] - tr[(c+a)&127])^2 ; out[c] is wave-uniform ->
    // v_readlane from registers (no LDS); tr reads are per-lane, the two
    // offsets (+0,+64 dwords) pair into ds_read2_b32.
    float d0 = 0.f, d1 = 0.f;
    #pragma unroll 8
    for (int c = 0; c < 64; ++c) {
        const float oc = readlane_f(o_lo, c);
        const float x0 = tw[c + l];
        const float x1 = tw[c + l + 64];
        const float u0 = oc - x0, u1 = oc - x1;
        d0 = fmaf(u0, u0, d0);
        d1 = fmaf(u1, u1, d1);
    }
    #pragma unroll 8
    for (int c = 0; c < 64; ++c) {
        const float oc = readlane_f(o_hi, c);
        const float x0 = tw[c + 64 + l];
        const float x1 = tw[c + 128 + l];
        const float u0 = oc - x0, u1 = oc - x1;
        d0 = fmaf(u0, u0, d0);
        d1 = fmaf(u1, u1, d1);
    }

    // ---- argmin with first-index tie-break (sqrt is monotone; compare sq).
    float v0 = d0; int i0 = l;
    float v1 = d1; int i1 = l + 64;
    #pragma unroll
    for (int m = 32; m; m >>= 1) {
        float vo = __shfl_xor(v0, m); int io = __shfl_xor(i0, m);
        if (vo < v0 || (vo == v0 && io < i0)) { v0 = vo; i0 = io; }
        float vp = __shfl_xor(v1, m); int ip = __shfl_xor(i1, m);
        if (vp < v1 || (vp == v1 && ip < i1)) { v1 = vp; i1 = ip; }
    }
    const int bs = (v0 <= v1) ? i0 : i1;   // ties -> smaller index (group 0)

    // ---- peaks (max(rolled)==max(out), roll is a permutation) + MSE partial.
    float po = fmaxf(o_lo, o_hi);
    float pt = fmaxf(t_lo, t_hi);
    const float dl = o_lo - t_lo, dh = o_hi - t_hi;
    float ms = dl * dl + dh * dh;
    #pragma unroll
    for (int m = 32; m; m >>= 1) {
        po = fmaxf(po, __shfl_xor(po, m));
        pt = fmaxf(pt, __shfl_xor(pt, m));
        ms += __shfl_xor(ms, m);
    }
    const float scale = pt / po;

    // ---- detail: g = cgrad(rolled*scale) - cgrad(truth), circular.
    const float* ow = s_out[w];
    float gs = 0.f;
    #pragma unroll
    for (int k = 0; k < 2; ++k) {
        const int j = l + 64 * k;
        const float r0 = ow[(j     - bs) & 127] * scale;
        const float rm = ow[(j - 1 - bs) & 127] * scale;
        const float rp = ow[(j + 1 - bs) & 127] * scale;
        const float cgo = r0 - 0.5f * (rm + rp);
        const float tj = (k == 0) ? t_lo : t_hi;
        const float cgt = tj - 0.5f * (tw[(j - 1) & 127] + tw[(j + 1) & 127]);
        const float g = cgo - cgt;
        gs = fmaf(g, g, gs);
    }
    #pragma unroll
    for (int m = 32; m; m >>= 1) gs += __shfl_xor(gs, m);

    // ---- per-row scalars -> block combine -> 2 atomics -> last-block final.
    if (l == 0) {
        s_part[w][0] = 50.0f * (float)bs
                     + 100.0f * fabsf(scale - 1.0f)
                     + 0.1f * sqrtf(gs);
        s_part[w][1] = ms;
    }
    __syncthreads();
    if (tid == 0) {
        const float pa = s_part[0][0] + s_part[1][0] + s_part[2][0] + s_part[3][0];
        const float pb = s_part[0][1] + s_part[1][1] + s_part[2][1] + s_part[3][1];
        atomicAdd(&acc[0], pa);
        atomicAdd(&acc[1], pb);
        __threadfence();
        // d_ws is re-poisoned to 0xAA before every timed launch -> the counter
        // word starts at exactly 0xAAAAAAAA each call.
        unsigned old = atomicAdd((unsigned*)&acc[2], 1u);
        if (old == 0xAAAAAAAAu + (unsigned)(NBLK - 1)) {
            // device-scope atomic reads (L2-coherent across XCDs)
            const float A = atomicAdd(&acc[0], 0.0f);
            const float B = atomicAdd(&acc[1], 0.0f);
            out[0] = A + sqrtf(B);   // poison offset ~ -3e-13, negligible
        }
    }
}

extern "C" void kernel_launch(void* const* d_in, const int* in_sizes, int n_in,
                              void* d_out, int out_size, void* d_ws, size_t ws_size,
                              hipStream_t stream) {
    const float* outp = (const float*)d_in[0];  // 'output' (4096,128) fp32
    const float* trp  = (const float*)d_in[1];  // 'truth'  (4096,128) fp32
    float* res        = (float*)d_out;          // scalar fp32
    float* acc        = (float*)d_ws;           // [0]=A, [1]=B, [2]=counter

    loss3_fused<<<NBLK, 256, 0, stream>>>(outp, trp, acc, res);
}

// Round 4
// 66.481 us; speedup vs baseline: 1.5091x; 1.5091x over previous
//
#include <hip/hip_runtime.h>
#include <math.h>

// Problem constants: N=4096 rows, S=128 samples (fp32).
#define S 128
#define NROWS 4096
#define WPB 4                      // waves per block, 1 row per wave
#define NBLK (NROWS / WPB)         // 1024 blocks

__device__ __forceinline__ float readlane_f(float v, int lane) {
    return __uint_as_float(__builtin_amdgcn_readlane(__float_as_uint(v), lane));
}

// Kernel 1: one wave per row. argmax of circular cross-correlation
// (== argmin of shift L2 distance: ||out||, ||tr|| are shift-invariant),
// then scale / detail / MSE partials. Per-block partials go to distinct
// d_ws slots -- NO global atomics (round-2 lesson: 3x1024 same-line device
// atomics serialized into a ~40us tail at 13% occupancy).
__global__ __launch_bounds__(256) void loss3_rows(
    const float* __restrict__ outp,
    const float* __restrict__ trp,
    float* __restrict__ part /* [NBLK][2] */) {

    __shared__ float s_tr2[WPB][2 * S];   // truth doubled for circular windows
    __shared__ float s_out[WPB][S];       // output row (detail phase)
    __shared__ float s_part[WPB][2];

    const int tid = threadIdx.x;
    const int w = tid >> 6;       // wave id = row within block
    const int l = tid & 63;       // lane
    const int row = blockIdx.x * WPB + w;

    const float* orow = outp + (size_t)row * S;
    const float* trow = trp  + (size_t)row * S;

    const float o_lo = orow[l], o_hi = orow[l + 64];
    const float t_lo = trow[l], t_hi = trow[l + 64];

    s_out[w][l]       = o_lo;  s_out[w][l + 64]  = o_hi;
    s_tr2[w][l]       = t_lo;  s_tr2[w][l + 64]  = t_hi;
    s_tr2[w][l + 128] = t_lo;  s_tr2[w][l + 192] = t_hi;

    // ROUND-3 LESSON: this barrier is REQUIRED even though each wave only
    // reads its own staged region. Without it ~15% of waves read un-landed
    // data (all-equal corr -> bestShift=0, absmax 1.97e6 == 50*619*63.5).
    __syncthreads();

    const float* tw = s_tr2[w];

    // corr[a] = sum_c out[c] * tr[(c+a)&127]; lane l computes a=l and a=l+64.
    // out[c] is wave-uniform -> v_readlane (register, off the LDS pipe); the
    // two tr reads pair into ds_read2_b32 with immediate dword offsets.
    float c0 = 0.f, c1 = 0.f;
    #pragma unroll
    for (int c = 0; c < 64; ++c) {
        const float oc = readlane_f(o_lo, c);
        c0 = fmaf(oc, tw[c + l], c0);
        c1 = fmaf(oc, tw[c + l + 64], c1);
    }
    #pragma unroll
    for (int c = 0; c < 64; ++c) {
        const float oc = readlane_f(o_hi, c);
        c0 = fmaf(oc, tw[c + 64 + l], c0);
        c1 = fmaf(oc, tw[c + 128 + l], c1);
    }

    // argmax corr with first-index tie-break (matches jnp.argmin semantics
    // through the monotone map dist = Eo + Et - 2*corr).
    float v0 = c0; int i0 = l;
    float v1 = c1; int i1 = l + 64;
    #pragma unroll
    for (int m = 32; m; m >>= 1) {
        float vo = __shfl_xor(v0, m); int io = __shfl_xor(i0, m);
        if (vo > v0 || (vo == v0 && io < i0)) { v0 = vo; i0 = io; }
        float vp = __shfl_xor(v1, m); int ip = __shfl_xor(i1, m);
        if (vp > v1 || (vp == v1 && ip < i1)) { v1 = vp; i1 = ip; }
    }
    const int bs = (v0 >= v1) ? i0 : i1;   // ties -> smaller index (group 0)

    // Peaks (max(rolled)==max(out): roll is a permutation) + MSE partial.
    float po = fmaxf(o_lo, o_hi);
    float pt = fmaxf(t_lo, t_hi);
    const float dl = o_lo - t_lo, dh = o_hi - t_hi;
    float ms = dl * dl + dh * dh;
    #pragma unroll
    for (int m = 32; m; m >>= 1) {
        po = fmaxf(po, __shfl_xor(po, m));
        pt = fmaxf(pt, __shfl_xor(pt, m));
        ms += __shfl_xor(ms, m);
    }
    const float scale = pt / po;

    // Detail: g = cgrad(rolled*scale) - cgrad(truth), circular.
    const float* ow = s_out[w];
    float gs = 0.f;
    #pragma unroll
    for (int k = 0; k < 2; ++k) {
        const int j = l + 64 * k;
        const float r0 = ow[(j     - bs) & 127] * scale;
        const float rm = ow[(j - 1 - bs) & 127] * scale;
        const float rp = ow[(j + 1 - bs) & 127] * scale;
        const float cgo = r0 - 0.5f * (rm + rp);
        const float tj = (k == 0) ? t_lo : t_hi;
        const float cgt = tj - 0.5f * (tw[(j - 1) & 127] + tw[(j + 1) & 127]);
        const float g = cgo - cgt;
        gs = fmaf(g, g, gs);
    }
    #pragma unroll
    for (int m = 32; m; m >>= 1) gs += __shfl_xor(gs, m);

    if (l == 0) {
        s_part[w][0] = 50.0f * (float)bs
                     + 100.0f * fabsf(scale - 1.0f)
                     + 0.1f * sqrtf(gs);
        s_part[w][1] = ms;
    }
    __syncthreads();
    if (tid == 0) {
        float2 p;
        p.x = s_part[0][0] + s_part[1][0] + s_part[2][0] + s_part[3][0];
        p.y = s_part[0][1] + s_part[1][1] + s_part[2][1] + s_part[3][1];
        ((float2*)part)[blockIdx.x] = p;   // plain store, distinct address
    }
}

// Kernel 2: deterministic reduction of 1024 block partials -> scalar.
__global__ __launch_bounds__(256) void loss3_reduce(
    const float* __restrict__ part, float* __restrict__ out) {

    __shared__ double shA[256];
    __shared__ double shB[256];

    const int t = threadIdx.x;
    double A = 0.0, B = 0.0;
    #pragma unroll
    for (int k = 0; k < NBLK / 256; ++k) {
        const float2 p = ((const float2*)part)[t + 256 * k];
        A += (double)p.x;
        B += (double)p.y;
    }
    shA[t] = A; shB[t] = B;
    __syncthreads();
    for (int off = 128; off > 0; off >>= 1) {
        if (t < off) { shA[t] += shA[t + off]; shB[t] += shB[t + off]; }
        __syncthreads();
    }
    if (t == 0) out[0] = (float)(shA[0] + sqrt(shB[0]));
}

extern "C" void kernel_launch(void* const* d_in, const int* in_sizes, int n_in,
                              void* d_out, int out_size, void* d_ws, size_t ws_size,
                              hipStream_t stream) {
    const float* outp = (const float*)d_in[0];  // 'output' (4096,128) fp32
    const float* trp  = (const float*)d_in[1];  // 'truth'  (4096,128) fp32
    float* res        = (float*)d_out;          // scalar fp32
    float* part       = (float*)d_ws;           // NBLK*2 floats = 8 KiB

    loss3_rows<<<NBLK, 256, 0, stream>>>(outp, trp, part);
    loss3_reduce<<<1, 256, 0, stream>>>(part, res);
}

// Round 5
// 64.234 us; speedup vs baseline: 1.5619x; 1.0350x over previous
//
#include <hip/hip_runtime.h>
#include <math.h>

// Problem constants: N=4096 rows, S=128 samples (fp32).
#define S 128
#define NROWS 4096
#define WPB 4                      // waves per block, 1 row per wave
#define NBLK (NROWS / WPB)         // 1024 blocks

__device__ __forceinline__ float readlane_f(float v, int lane) {
    return __uint_as_float(__builtin_amdgcn_readlane(__float_as_uint(v), lane));
}

// Kernel 1: one wave per row. argmax of circular cross-correlation
// (== argmin of shift L2 distance: ||out||, ||tr|| are shift-invariant),
// then scale / detail / MSE partials. Plain per-block stores, no atomics
// (round 2: 3x1024 same-line device atomics -> ~40us serialized tail).
//
// DS-halving identity (this round): t0 = tr[(k+l)&127] multiplies out[k]
// in corr[l] AND out[k+64] in corr[l+64] (indices wrap); t1 =
// tr[(k+l+64)&127] is the mirror. One ds_read2_b32 -> 4 FMAs.
__global__ __launch_bounds__(256) void loss3_rows(
    const float* __restrict__ outp,
    const float* __restrict__ trp,
    float* __restrict__ part /* [NBLK][2] */) {

    __shared__ float s_tr2[WPB][2 * S];   // truth doubled for circular windows
    __shared__ float s_out[WPB][S];       // output row (detail phase)
    __shared__ float s_part[WPB][2];

    const int tid = threadIdx.x;
    const int w = tid >> 6;       // wave id = row within block
    const int l = tid & 63;       // lane
    const int row = blockIdx.x * WPB + w;

    const float* orow = outp + (size_t)row * S;
    const float* trow = trp  + (size_t)row * S;

    const float o_lo = orow[l], o_hi = orow[l + 64];
    const float t_lo = trow[l], t_hi = trow[l + 64];

    s_out[w][l]       = o_lo;  s_out[w][l + 64]  = o_hi;
    s_tr2[w][l]       = t_lo;  s_tr2[w][l + 64]  = t_hi;
    s_tr2[w][l + 128] = t_lo;  s_tr2[w][l + 192] = t_hi;

    // ROUND-3 LESSON: this barrier is REQUIRED even though each wave only
    // reads its own staged region (without it ~15% of waves read un-landed
    // data -> bestShift=0 everywhere -> absmax 1.97e6).
    __syncthreads();

    const float* tw   = s_tr2[w];
    const float* tw_l = tw + l;   // single address register; imm dword offsets

    // corr[a] for a=l (c0) and a=l+64 (c1):
    //   t0 = tw_l[k]    = tr[(k+l)&127]
    //   t1 = tw_l[k+64] = tr[(k+l+64)&127]      (one ds_read2_b32)
    //   u0 = out[k] (readlane o_lo,k), u1 = out[k+64] (readlane o_hi,k)
    //   c0 += u0*t0 + u1*t1 ;  c1 += u0*t1 + u1*t0
    float c0 = 0.f, c1 = 0.f;
    #pragma unroll
    for (int k = 0; k < 64; ++k) {
        const float t0 = tw_l[k];
        const float t1 = tw_l[k + 64];
        const float u0 = readlane_f(o_lo, k);
        const float u1 = readlane_f(o_hi, k);
        c0 = fmaf(u0, t0, c0);
        c0 = fmaf(u1, t1, c0);
        c1 = fmaf(u0, t1, c1);
        c1 = fmaf(u1, t0, c1);
    }

    // argmax corr with first-index tie-break (matches jnp.argmin through the
    // monotone map dist = Eo + Et - 2*corr).
    float v0 = c0; int i0 = l;
    float v1 = c1; int i1 = l + 64;
    #pragma unroll
    for (int m = 32; m; m >>= 1) {
        float vo = __shfl_xor(v0, m); int io = __shfl_xor(i0, m);
        if (vo > v0 || (vo == v0 && io < i0)) { v0 = vo; i0 = io; }
        float vp = __shfl_xor(v1, m); int ip = __shfl_xor(i1, m);
        if (vp > v1 || (vp == v1 && ip < i1)) { v1 = vp; i1 = ip; }
    }
    const int bs = (v0 >= v1) ? i0 : i1;   // ties -> smaller index (group 0)

    // Peaks (max(rolled)==max(out): roll is a permutation) + MSE partial.
    float po = fmaxf(o_lo, o_hi);
    float pt = fmaxf(t_lo, t_hi);
    const float dl = o_lo - t_lo, dh = o_hi - t_hi;
    float ms = dl * dl + dh * dh;
    #pragma unroll
    for (int m = 32; m; m >>= 1) {
        po = fmaxf(po, __shfl_xor(po, m));
        pt = fmaxf(pt, __shfl_xor(pt, m));
        ms += __shfl_xor(ms, m);
    }
    const float scale = pt / po;

    // Detail: g = cgrad(rolled*scale) - cgrad(truth), circular.
    const float* ow = s_out[w];
    float gs = 0.f;
    #pragma unroll
    for (int k = 0; k < 2; ++k) {
        const int j = l + 64 * k;
        const float r0 = ow[(j     - bs) & 127] * scale;
        const float rm = ow[(j - 1 - bs) & 127] * scale;
        const float rp = ow[(j + 1 - bs) & 127] * scale;
        const float cgo = r0 - 0.5f * (rm + rp);
        const float tj = (k == 0) ? t_lo : t_hi;
        const float cgt = tj - 0.5f * (tw[(j - 1) & 127] + tw[(j + 1) & 127]);
        const float g = cgo - cgt;
        gs = fmaf(g, g, gs);
    }
    #pragma unroll
    for (int m = 32; m; m >>= 1) gs += __shfl_xor(gs, m);

    if (l == 0) {
        s_part[w][0] = 50.0f * (float)bs
                     + 100.0f * fabsf(scale - 1.0f)
                     + 0.1f * sqrtf(gs);
        s_part[w][1] = ms;
    }
    __syncthreads();
    if (tid == 0) {
        float2 p;
        p.x = s_part[0][0] + s_part[1][0] + s_part[2][0] + s_part[3][0];
        p.y = s_part[0][1] + s_part[1][1] + s_part[2][1] + s_part[3][1];
        ((float2*)part)[blockIdx.x] = p;   // plain store, distinct address
    }
}

// Kernel 2: deterministic reduction of 1024 block partials -> scalar.
__global__ __launch_bounds__(256) void loss3_reduce(
    const float* __restrict__ part, float* __restrict__ out) {

    __shared__ double shA[256];
    __shared__ double shB[256];

    const int t = threadIdx.x;
    double A = 0.0, B = 0.0;
    #pragma unroll
    for (int k = 0; k < NBLK / 256; ++k) {
        const float2 p = ((const float2*)part)[t + 256 * k];
        A += (double)p.x;
        B += (double)p.y;
    }
    shA[t] = A; shB[t] = B;
    __syncthreads();
    for (int off = 128; off > 0; off >>= 1) {
        if (t < off) { shA[t] += shA[t + off]; shB[t] += shB[t + off]; }
        __syncthreads();
    }
    if (t == 0) out[0] = (float)(shA[0] + sqrt(shB[0]));
}

extern "C" void kernel_launch(void* const* d_in, const int* in_sizes, int n_in,
                              void* d_out, int out_size, void* d_ws, size_t ws_size,
                              hipStream_t stream) {
    const float* outp = (const float*)d_in[0];  // 'output' (4096,128) fp32
    const float* trp  = (const float*)d_in[1];  // 'truth'  (4096,128) fp32
    float* res        = (float*)d_out;          // scalar fp32
    float* part       = (float*)d_ws;           // NBLK*2 floats = 8 KiB

    loss3_rows<<<NBLK, 256, 0, stream>>>(outp, trp, part);
    loss3_reduce<<<1, 256, 0, stream>>>(part, res);
}